// Round 2
// baseline (442.079 us; speedup 1.0000x reference)
//
#include <hip/hip_runtime.h>

typedef __attribute__((ext_vector_type(8))) short short8;
typedef __attribute__((ext_vector_type(4))) float floatx4;
typedef unsigned short u16;
typedef unsigned int u32;

#define GETC(v, hw) ((hw)==0 ? (v).x : (hw)==1 ? (v).y : (hw)==2 ? (v).z : (v).w)
#define MFMA16(a,b,c) __builtin_amdgcn_mfma_f32_16x16x32_bf16((a),(b),(c),0,0,0)

__device__ __forceinline__ u16 f2bf(float f) {
  u32 u = __builtin_bit_cast(u32, f);
  u += 0x7fffu + ((u >> 16) & 1u);   // RNE; inputs finite
  return (u16)(u >> 16);
}
__device__ __forceinline__ u32 pk2(float a, float b) {
  return (u32)f2bf(a) | ((u32)f2bf(b) << 16);
}

// ---------- batched 64x64-tile transpose, fp32 in -> bf16 out ----------
// in: [Z][NI][NJ] fp32  ->  out: [Z][NJ][NI] bf16
__global__ __launch_bounds__(256) void tk_f2b(const float* __restrict__ in,
                                              u16* __restrict__ out,
                                              int NI, int NJ) {
  __shared__ float tile[64][65];
  const int tid = threadIdx.x;
  const long long base = (long long)blockIdx.z * NI * NJ;
  const int i0 = blockIdx.x * 64, j0 = blockIdx.y * 64;
#pragma unroll
  for (int p = 0; p < 4; ++p) {
    int i = p * 16 + (tid >> 4);
    int jl = (tid & 15) * 4;
    float4 v = *(const float4*)(in + base + (long long)(i0 + i) * NJ + j0 + jl);
    tile[i][jl + 0] = v.x; tile[i][jl + 1] = v.y;
    tile[i][jl + 2] = v.z; tile[i][jl + 3] = v.w;
  }
  __syncthreads();
#pragma unroll
  for (int p = 0; p < 4; ++p) {
    int j = p * 16 + (tid >> 4);
    int il = (tid & 15) * 4;
    float e0 = tile[il + 0][j], e1 = tile[il + 1][j];
    float e2 = tile[il + 2][j], e3 = tile[il + 3][j];
    uint2 o; o.x = pk2(e0, e1); o.y = pk2(e2, e3);
    *(uint2*)(out + base + (long long)(j0 + j) * NI + i0 + il) = o;
  }
}

// ---------- batched 64x64-tile transpose, fp32 -> fp32 ----------
__global__ __launch_bounds__(256) void tk_f2f(const float* __restrict__ in,
                                              float* __restrict__ out,
                                              int NI, int NJ) {
  __shared__ float tile[64][65];
  const int tid = threadIdx.x;
  const long long base = (long long)blockIdx.z * NI * NJ;
  const int i0 = blockIdx.x * 64, j0 = blockIdx.y * 64;
#pragma unroll
  for (int p = 0; p < 4; ++p) {
    int i = p * 16 + (tid >> 4);
    int jl = (tid & 15) * 4;
    float4 v = *(const float4*)(in + base + (long long)(i0 + i) * NJ + j0 + jl);
    tile[i][jl + 0] = v.x; tile[i][jl + 1] = v.y;
    tile[i][jl + 2] = v.z; tile[i][jl + 3] = v.w;
  }
  __syncthreads();
#pragma unroll
  for (int p = 0; p < 4; ++p) {
    int j = p * 16 + (tid >> 4);
    int il = (tid & 15) * 4;
    float4 o;
    o.x = tile[il + 0][j]; o.y = tile[il + 1][j];
    o.z = tile[il + 2][j]; o.w = tile[il + 3][j];
    *(float4*)(out + base + (long long)(j0 + j) * NI + i0 + il) = o;
  }
}

// ---------------- fused GCN kernel: one WG per (b,m) ----------------
// xT: [b*64+m][32 f][256 n] bf16 (ws).  Bases: [b][m][256 n][256 v] fp32.
// W: [64][224] fp32.  Output yT: [b*64+m][64 o][256 c] fp32 (ws).
__global__ __launch_bounds__(256, 1) void gcn_main(
    const u16* __restrict__ xT, const float* __restrict__ A0,
    const float* __restrict__ A1, const float* __restrict__ A2,
    const float* __restrict__ Wm, const float* __restrict__ bias,
    float* __restrict__ yT) {
  // LDS: fragA (full base, B-operand frag-packed, XOR-swizzled) 128K
  //      fragX1 (x1 as A-operand frags) 16K ; fragH (block as B-op frags) 16K
  __shared__ __align__(16) unsigned char smem[163840];
  unsigned char* fragA  = smem;
  unsigned char* fragX1 = smem + 131072;
  unsigned char* fragH  = smem + 147456;

  const int tid  = threadIdx.x;
  const int w    = tid >> 6;       // wave id: columns 64w..64w+63
  const int lane = tid & 63;
  const int q    = lane >> 4;
  const int s    = lane & 15;
  const int wg   = blockIdx.x;     // b*64 + m

  const float* Ab0 = A0 + (size_t)wg * 65536;
  const float* Ab1 = A1 + (size_t)wg * 65536;
  const float* Ab2 = A2 + (size_t)wg * 65536;

  // ---- x A-operand fragments (all 32x256), straight from xT (bf16), in regs
  short8 xa[2][8];
  const u16* xp = xT + (size_t)wg * 8192;
#pragma unroll
  for (int mr = 0; mr < 2; ++mr)
#pragma unroll
    for (int k = 0; k < 8; ++k)
      xa[mr][k] = *(const short8*)(xp + (16 * mr + s) * 256 + 32 * k + 8 * q);

  // ---- staging registers for one base: fp32 coalesced loads -> packed bf16
  const int bn = tid >> 5, bv = tid & 31;
  const int v0 = bv * 8;
  uint4 stg[4][8];                 // each = 8 bf16 of one row-segment
  auto loadStage = [&](const float* Ai) {
#pragma unroll
    for (int p = 0; p < 4; ++p) {
      int n0 = p * 64 + bn * 8;
#pragma unroll
      for (int jj = 0; jj < 8; ++jj) {
        const float* rp = Ai + (size_t)(n0 + jj) * 256 + v0;
        float4 lo = *(const float4*)rp;
        float4 hi = *(const float4*)(rp + 4);
        uint4 r;
        r.x = pk2(lo.x, lo.y); r.y = pk2(lo.z, lo.w);
        r.z = pk2(hi.x, hi.y); r.w = pk2(hi.z, hi.w);
        stg[p][jj] = r;
      }
    }
  };
  // 8x8 register transpose (v_perm) -> swizzled fragment-packed LDS
  auto stageToLds = [&]() {
#pragma unroll
    for (int p = 0; p < 4; ++p) {
      int n0 = p * 64 + bn * 8;
      int kst = n0 >> 5, qst = (n0 >> 3) & 3;
#pragma unroll
      for (int i = 0; i < 8; ++i) {
        int v = v0 + i;
        int tg = v >> 4, sl = v & 15;
        u32 sel = (i & 1) ? 0x07060302u : 0x05040100u;
        const int hw = i >> 1;
        u32 d0 = __builtin_amdgcn_perm(GETC(stg[p][1], hw), GETC(stg[p][0], hw), sel);
        u32 d1 = __builtin_amdgcn_perm(GETC(stg[p][3], hw), GETC(stg[p][2], hw), sel);
        u32 d2 = __builtin_amdgcn_perm(GETC(stg[p][5], hw), GETC(stg[p][4], hw), sel);
        u32 d3 = __builtin_amdgcn_perm(GETC(stg[p][7], hw), GETC(stg[p][6], hw), sel);
        int phys = (qst * 16 + sl) ^ (tg & 7);   // write-conflict-free swizzle
        uint4 val; val.x = d0; val.y = d1; val.z = d2; val.w = d3;
        *(uint4*)(fragA + (((kst * 16 + tg) * 64 + phys) << 4)) = val;
      }
    }
  };

  loadStage(Ab0);

  // ---- write x into fragH (B-operand layout); wave w owns ksteps 2w,2w+1
#pragma unroll
  for (int mr = 0; mr < 2; ++mr)
#pragma unroll
    for (int kk = 0; kk < 8; ++kk) {
      if ((kk >> 1) != w) continue;
#pragma unroll
      for (int jj = 0; jj < 8; ++jj) {
        int c = 32 * kk + 8 * q + jj;
        int f = 16 * mr + s;
        int off = (((c >> 4) * 64 + (f >> 3) * 16 + (c & 15)) << 4) + 2 * (f & 7);
        *(u16*)(fragH + off) = (u16)xa[mr][kk][jj];
      }
    }

  floatx4 yacc[4][4];
#pragma unroll
  for (int mr = 0; mr < 4; ++mr)
#pragma unroll
    for (int t = 0; t < 4; ++t) yacc[mr][t] = (floatx4){0.f, 0.f, 0.f, 0.f};

  auto finalGemm = [&](int jblk) {   // yacc += W[:, 32j:32j+32] * fragH
    short8 wf[4], hf[4];
#pragma unroll
    for (int mr = 0; mr < 4; ++mr) {
      const float* wp = Wm + (16 * mr + s) * 224 + 32 * jblk + 8 * q;
      float4 lo = *(const float4*)wp;
      float4 hi = *(const float4*)(wp + 4);
      union { uint4 u; short8 v; } r;
      r.u.x = pk2(lo.x, lo.y); r.u.y = pk2(lo.z, lo.w);
      r.u.z = pk2(hi.x, hi.y); r.u.w = pk2(hi.z, hi.w);
      wf[mr] = r.v;
    }
#pragma unroll
    for (int t = 0; t < 4; ++t)
      hf[t] = *(const short8*)(fragH + (((4 * w + t) * 64 + lane) << 4));
#pragma unroll
    for (int mr = 0; mr < 4; ++mr)
#pragma unroll
      for (int t = 0; t < 4; ++t)
        yacc[mr][t] = MFMA16(wf[mr], hf[t], yacc[mr][t]);
  };
  auto writeH = [&](const floatx4 (&acc)[2][4]) {  // C-layout acc -> B-op frags
#pragma unroll
    for (int mr = 0; mr < 2; ++mr)
#pragma unroll
      for (int t = 0; t < 4; ++t)
#pragma unroll
        for (int r = 0; r < 4; ++r) {
          int F = 16 * mr + 4 * q + r;
          int off = (((4 * w + t) * 64 + (F >> 3) * 16 + s) << 4) + 2 * (F & 7);
          *(u16*)(fragH + off) = f2bf(acc[mr][t][r]);
        }
  };
  auto writeX1 = [&](const floatx4 (&acc)[2][4]) { // C-layout acc -> A-op frags
#pragma unroll
    for (int mr = 0; mr < 2; ++mr)
#pragma unroll
      for (int t = 0; t < 4; ++t) {
        int Cc = 64 * w + 16 * t + s;
        int kk = Cc >> 5, qq = (Cc >> 3) & 3, jj = Cc & 7;
#pragma unroll
        for (int r = 0; r < 4; ++r) {
          int off = (((mr * 8 + kk) * 64 + qq * 16 + 4 * q + r) << 4) + 2 * jj;
          *(u16*)(fragX1 + off) = f2bf(acc[mr][t][r]);
        }
      }
  };

  __syncthreads();
  finalGemm(0);   // y += W0 * x

#pragma unroll 1
  for (int ib = 0; ib < 3; ++ib) {
    __syncthreads();
    stageToLds();                          // base ib -> fragA
    if (ib < 2) loadStage(ib == 0 ? Ab1 : Ab2);  // prefetch overlaps compute
    __syncthreads();

    // hop1: x1 = x * A
    floatx4 h1[2][4];
#pragma unroll
    for (int mr = 0; mr < 2; ++mr)
#pragma unroll
      for (int t = 0; t < 4; ++t) h1[mr][t] = (floatx4){0.f, 0.f, 0.f, 0.f};
#pragma unroll
    for (int k = 0; k < 8; ++k) {
      short8 bf[4];
#pragma unroll
      for (int t = 0; t < 4; ++t) {
        int tg = 4 * w + t;
        bf[t] = *(const short8*)(fragA + (((k * 16 + tg) * 64 + (lane ^ (tg & 7))) << 4));
      }
#pragma unroll
      for (int mr = 0; mr < 2; ++mr)
#pragma unroll
        for (int t = 0; t < 4; ++t)
          h1[mr][t] = MFMA16(xa[mr][k], bf[t], h1[mr][t]);
    }
    writeX1(h1);
    writeH(h1);
    __syncthreads();
    finalGemm(1 + 2 * ib);                 // y += W1_i * x1

    // hop2: x2 = x1 * A
    floatx4 h2[2][4];
#pragma unroll
    for (int mr = 0; mr < 2; ++mr)
#pragma unroll
      for (int t = 0; t < 4; ++t) h2[mr][t] = (floatx4){0.f, 0.f, 0.f, 0.f};
#pragma unroll
    for (int k = 0; k < 8; ++k) {
      short8 a0 = *(const short8*)(fragX1 + ((k * 64 + lane) << 4));
      short8 a1 = *(const short8*)(fragX1 + (((8 + k) * 64 + lane) << 4));
      short8 bf[4];
#pragma unroll
      for (int t = 0; t < 4; ++t) {
        int tg = 4 * w + t;
        bf[t] = *(const short8*)(fragA + (((k * 16 + tg) * 64 + (lane ^ (tg & 7))) << 4));
      }
#pragma unroll
      for (int t = 0; t < 4; ++t) {
        h2[0][t] = MFMA16(a0, bf[t], h2[0][t]);
        h2[1][t] = MFMA16(a1, bf[t], h2[1][t]);
      }
    }
    __syncthreads();                       // finalGemm(x1) reads done
    writeH(h2);
    __syncthreads();
    finalGemm(2 + 2 * ib);                 // y += W2_i * x2
  }

  // ---- epilogue: bias + store yT[wg][o][c] (fp32)
  float* yp = yT + (size_t)wg * 16384;
#pragma unroll
  for (int mr = 0; mr < 4; ++mr) {
    float br[4];
#pragma unroll
    for (int r = 0; r < 4; ++r) br[r] = bias[16 * mr + 4 * q + r];
#pragma unroll
    for (int t = 0; t < 4; ++t) {
      int c = 64 * w + 16 * t + s;
#pragma unroll
      for (int r = 0; r < 4; ++r) {
        int o = 16 * mr + 4 * q + r;
        yp[o * 256 + c] = yacc[mr][t][r] + br[r];
      }
    }
  }
}

extern "C" void kernel_launch(void* const* d_in, const int* in_sizes, int n_in,
                              void* d_out, int out_size, void* d_ws, size_t ws_size,
                              hipStream_t stream) {
  const float* x    = (const float*)d_in[0];
  const float* b0   = (const float*)d_in[1];
  const float* b1   = (const float*)d_in[2];
  const float* b2   = (const float*)d_in[3];
  const float* Wm   = (const float*)d_in[4];
  const float* bias = (const float*)d_in[5];
  u16*   xT  = (u16*)d_ws;                          //  8 MB bf16: [b*64+m][f][n]
  float* yTs = (float*)((char*)d_ws + 8388608);     // 33.5 MB fp32: [b*64+m][o][c]
  float* out = (float*)d_out;

  // K1: x fp32 [b][f*256+n][m] -> xT bf16 [b][m][f*256+n]
  tk_f2b<<<dim3(128, 1, 8), 256, 0, stream>>>(x, xT, 8192, 64);
  // K2: fused nconv chain + channel mix
  gcn_main<<<dim3(512), 256, 0, stream>>>(xT, b0, b1, b2, Wm, bias, yTs);
  // K3: yT fp32 [b][m][o*256+c] -> y fp32 [b][o*256+c][m]
  tk_f2f<<<dim3(1, 256, 8), 256, 0, stream>>>(yTs, out, 64, 16384);
}